// Round 8
// baseline (59.225 us; speedup 1.0000x reference)
//
#include <hip/hip_runtime.h>
#include <math.h>

#define HIDDEN 1024
#define VOCAB  50257
#define MAXLEN 64

__device__ __forceinline__ float wave_reduce_sum(float v) {
    #pragma unroll
    for (int off = 32; off > 0; off >>= 1)
        v += __shfl_down(v, off, 64);
    return v;
}

// A: 64 blocks x 256 threads. Block m: s_m = dot(concat(emb_row,h0), attn_W[m]) + b;
// e_m = exp(s_m)  (softmax shift-invariance: scores ~N(0,1), no max needed);
// atomicAdd e_m*enc[m][:] into ctx_num, e_m into den.
__global__ __launch_bounds__(256) void k_score_ctx(
    const int* __restrict__ token,
    const float* __restrict__ emb,
    const float* __restrict__ hidden,
    const float* __restrict__ attn_W,
    const float* __restrict__ attn_b,
    const float* __restrict__ enc,
    float* __restrict__ ws_ctxnum,   // [1024] (zeroed)
    float* __restrict__ ws_den,      // [1]    (zeroed)
    float* __restrict__ ws_e)        // [64]
{
    const int m = blockIdx.x;
    const int t = threadIdx.x;
    const int wid = t >> 6, lane = t & 63;
    const float* erow = emb + (size_t)token[0] * HIDDEN;
    const float4* Wrow = (const float4*)(attn_W + (size_t)m * 2 * HIDDEN);
    float acc = 0.f;
    #pragma unroll
    for (int it = 0; it < 2; ++it) {
        int i = t + it * 256;            // 0..511 float4s
        float4 w4 = Wrow[i];
        int k = i * 4;
        const float* src = (k < HIDDEN) ? (erow + k) : (hidden + k - HIDDEN);
        float4 c4 = *(const float4*)src;
        acc += w4.x * c4.x + w4.y * c4.y + w4.z * c4.z + w4.w * c4.w;
    }
    __shared__ float part[4];
    __shared__ float e_sh;
    acc = wave_reduce_sum(acc);
    if (lane == 0) part[wid] = acc;
    __syncthreads();
    if (t == 0) {
        float e = expf(part[0] + part[1] + part[2] + part[3] + attn_b[m]);
        ws_e[m] = e;
        e_sh = e;
        atomicAdd(ws_den, e);
    }
    __syncthreads();
    const float e = e_sh;
    const int h = t * 4;
    const float4 ev = *(const float4*)(enc + (size_t)m * HIDDEN + h);
    atomicAdd(&ws_ctxnum[h + 0], e * ev.x);
    atomicAdd(&ws_ctxnum[h + 1], e * ev.y);
    atomicAdd(&ws_ctxnum[h + 2], e * ev.z);
    atomicAdd(&ws_ctxnum[h + 3], e * ev.w);
}

// B: 256 blocks x 256 threads (wave per row j):
// x[j] = relu( dot(emb_row, W[:,0:1024]) + dot(ctx_num, W[:,1024:2048])/den + b[j] )
// block 0 / wave 0 also writes out_attn = e/den.
__global__ __launch_bounds__(256) void k_combine(
    const int* __restrict__ token,
    const float* __restrict__ emb,
    const float* __restrict__ ws_ctxnum,
    const float* __restrict__ ws_den,
    const float* __restrict__ ws_e,
    const float* __restrict__ comb_W,
    const float* __restrict__ comb_b,
    float* __restrict__ ws_x,
    float* __restrict__ out_attn)
{
    const int wid = threadIdx.x >> 6, lane = threadIdx.x & 63;
    const int j = blockIdx.x * 4 + wid;
    const float inv_den = 1.0f / ws_den[0];
    if (blockIdx.x == 0 && wid == 0)
        out_attn[lane] = ws_e[lane] * inv_den;
    const float4* e4 = (const float4*)(emb + (size_t)token[0] * HIDDEN);
    const float4* c4 = (const float4*)ws_ctxnum;
    const float4* Wr = (const float4*)(comb_W + (size_t)j * 2 * HIDDEN);
    float acc_e = 0.f, acc_c = 0.f;
    #pragma unroll
    for (int it = 0; it < 4; ++it) {
        int i = lane + it * 64;          // emb half: 0..255
        float4 a = Wr[i];
        float4 c = e4[i];
        acc_e += a.x * c.x + a.y * c.y + a.z * c.z + a.w * c.w;
    }
    #pragma unroll
    for (int it = 0; it < 4; ++it) {
        int i = lane + it * 64;          // ctx half: 256..511
        float4 a = Wr[i + 256];
        float4 c = c4[i];
        acc_c += a.x * c.x + a.y * c.y + a.z * c.z + a.w * c.w;
    }
    float acc = acc_e + acc_c * inv_den;
    acc = wave_reduce_sum(acc);
    if (lane == 0) ws_x[j] = fmaxf(acc + comb_b[j], 0.f);
}

// C: 1024 blocks x 384 threads: block j, wave q computes gate-dot q; thread 0 combines.
__global__ __launch_bounds__(384) void k_gru(
    const float* __restrict__ ws_x,
    const float* __restrict__ hidden,
    const float* __restrict__ W_ih,
    const float* __restrict__ W_hh,
    const float* __restrict__ b_ih,
    const float* __restrict__ b_hh,
    float* __restrict__ ws_h,
    float* __restrict__ out_h)
{
    __shared__ float dval[6];
    const int j = blockIdx.x;
    const int q = threadIdx.x >> 6, lane = threadIdx.x & 63;
    const float* row = (q < 3)
        ? (W_ih + (size_t)(j + q * HIDDEN) * HIDDEN)
        : (W_hh + (size_t)(j + (q - 3) * HIDDEN) * HIDDEN);
    const float* vec = (q < 3) ? ws_x : hidden;
    const float4* W4 = (const float4*)row;
    const float4* v4 = (const float4*)vec;
    float acc = 0.f;
    #pragma unroll
    for (int it = 0; it < 4; ++it) {
        int i = lane + it * 64;          // 0..255 float4s
        float4 a = W4[i];
        float4 b = v4[i];
        acc += a.x * b.x + a.y * b.y + a.z * b.z + a.w * b.w;
    }
    acc = wave_reduce_sum(acc);
    if (lane == 0) dval[q] = acc;
    __syncthreads();
    if (threadIdx.x == 0) {
        float i_r = dval[0] + b_ih[j];
        float i_z = dval[1] + b_ih[j + HIDDEN];
        float i_n = dval[2] + b_ih[j + 2 * HIDDEN];
        float h_r = dval[3] + b_hh[j];
        float h_z = dval[4] + b_hh[j + HIDDEN];
        float h_n = dval[5] + b_hh[j + 2 * HIDDEN];
        float r = 1.f / (1.f + expf(-(i_r + h_r)));
        float z = 1.f / (1.f + expf(-(i_z + h_z)));
        float n = tanhf(i_n + r * h_n);
        float h0v = hidden[j];
        float hn = (1.f - z) * n + z * h0v;
        ws_h[j] = hn;
        out_h[j] = hn;
    }
}

// D: logits, persistent grid-stride: 1024 blocks x 256 threads (4 blocks/CU
// resident), 4 rows/wave/iter, h in registers, ~3-4 iters per wave so the
// next batch of 16 dwordx4 issues while the current reduce drains.
__global__ __launch_bounds__(256) void k_logits(
    const float* __restrict__ ws_h,
    const float* __restrict__ out_W,
    const float* __restrict__ out_b,
    float* __restrict__ out_logits)
{
    const int t = threadIdx.x;
    const int wid = t >> 6, lane = t & 63;
    const float4* h4 = (const float4*)ws_h;
    const float4 hv0 = h4[lane];
    const float4 hv1 = h4[lane + 64];
    const float4 hv2 = h4[lane + 128];
    const float4 hv3 = h4[lane + 192];

    for (int base = blockIdx.x * 16 + wid * 4; base < VOCAB; base += gridDim.x * 16) {
        float acc[4];
        #pragma unroll
        for (int r = 0; r < 4; ++r) {
            int v = base + r;
            if (v > VOCAB - 1) v = VOCAB - 1;   // clamp: duplicate read, discarded
            const float4* W = (const float4*)(out_W + (size_t)v * HIDDEN);
            float4 a0 = W[lane];
            float4 a1 = W[lane + 64];
            float4 a2 = W[lane + 128];
            float4 a3 = W[lane + 192];
            float s;
            s  = a0.x * hv0.x + a0.y * hv0.y + a0.z * hv0.z + a0.w * hv0.w;
            s += a1.x * hv1.x + a1.y * hv1.y + a1.z * hv1.z + a1.w * hv1.w;
            s += a2.x * hv2.x + a2.y * hv2.y + a2.z * hv2.z + a2.w * hv2.w;
            s += a3.x * hv3.x + a3.y * hv3.y + a3.z * hv3.z + a3.w * hv3.w;
            acc[r] = s;
        }
        #pragma unroll
        for (int r = 0; r < 4; ++r)
            acc[r] = wave_reduce_sum(acc[r]);
        if (lane == 0) {
            #pragma unroll
            for (int r = 0; r < 4; ++r) {
                const int v = base + r;
                if (v < VOCAB) out_logits[v] = acc[r] + out_b[v];
            }
        }
    }
}

extern "C" void kernel_launch(void* const* d_in, const int* in_sizes, int n_in,
                              void* d_out, int out_size, void* d_ws, size_t ws_size,
                              hipStream_t stream) {
    const int*   token  = (const int*)d_in[0];
    const float* hidden = (const float*)d_in[1];
    const float* enc    = (const float*)d_in[2];
    const float* emb    = (const float*)d_in[3];
    const float* attn_W = (const float*)d_in[4];
    const float* attn_b = (const float*)d_in[5];
    const float* comb_W = (const float*)d_in[6];
    const float* comb_b = (const float*)d_in[7];
    const float* W_ih   = (const float*)d_in[8];
    const float* W_hh   = (const float*)d_in[9];
    const float* b_ih   = (const float*)d_in[10];
    const float* b_hh   = (const float*)d_in[11];
    const float* out_W  = (const float*)d_in[12];
    const float* out_b  = (const float*)d_in[13];

    float* out = (float*)d_out;
    float* out_logits = out;                       // [50257]
    float* out_h      = out + VOCAB;               // [1024]
    float* out_attn   = out + VOCAB + HIDDEN;      // [64]

    float* ws = (float*)d_ws;
    float* ws_ctxnum = ws;            // [1024]  zeroed each call
    float* ws_den    = ws + 1024;     // [1]     zeroed each call
    float* ws_e      = ws + 1056;     // [64]
    float* ws_x      = ws + 1152;     // [1024]
    float* ws_h      = ws + 2176;     // [1024]

    hipMemsetAsync(ws, 0, (1024 + 32) * sizeof(float), stream);
    k_score_ctx<<<MAXLEN, 256, 0, stream>>>(token, emb, hidden, attn_W, attn_b,
                                            enc, ws_ctxnum, ws_den, ws_e);
    k_combine<<<HIDDEN / 4, 256, 0, stream>>>(token, emb, ws_ctxnum, ws_den, ws_e,
                                              comb_W, comb_b, ws_x, out_attn);
    k_gru<<<HIDDEN, 384, 0, stream>>>(ws_x, hidden, W_ih, W_hh, b_ih, b_hh, ws_h, out_h);
    k_logits<<<1024, 256, 0, stream>>>(ws_h, out_W, out_b, out_logits);
}

// Round 9
// 57.626 us; speedup vs baseline: 1.0277x; 1.0277x over previous
//
#include <hip/hip_runtime.h>
#include <math.h>

#define HIDDEN 1024
#define VOCAB  50257
#define MAXLEN 64

__device__ __forceinline__ float wave_reduce_sum(float v) {
    #pragma unroll
    for (int off = 32; off > 0; off >>= 1)
        v += __shfl_down(v, off, 64);
    return v;
}

// K1: scores + softmax + context in ONE block (work is tiny & L2-resident;
// done ONCE — not redundantly like round 2). 1 block x 1024 threads.
__global__ __launch_bounds__(1024) void k_prelude(
    const int* __restrict__ token,
    const float* __restrict__ emb,
    const float* __restrict__ hidden,
    const float* __restrict__ enc,
    const float* __restrict__ attn_W,
    const float* __restrict__ attn_b,
    float* __restrict__ ws_ctx,
    float* __restrict__ out_attn)
{
    __shared__ float sc[MAXLEN];
    __shared__ float wsm[MAXLEN];
    const int t = threadIdx.x;
    const int w = t >> 6, lane = t & 63;
    const float4* e4 = (const float4*)(emb + (size_t)token[0] * HIDDEN);
    const float4* h4 = (const float4*)hidden;

    // scores: wave w -> rows 4w..4w+3 (16 waves cover all 64 rows)
    #pragma unroll
    for (int r = 0; r < 4; ++r) {
        const int m = w * 4 + r;
        const float4* Wr = (const float4*)(attn_W + (size_t)m * 2 * HIDDEN);
        float acc = 0.f;
        #pragma unroll
        for (int it = 0; it < 8; ++it) {
            int i = lane + it * 64;                 // 0..511 float4s
            float4 a = Wr[i];
            float4 c = (i < 256) ? e4[i] : h4[i - 256];
            acc += a.x * c.x + a.y * c.y + a.z * c.z + a.w * c.w;
        }
        acc = wave_reduce_sum(acc);
        if (lane == 0) sc[m] = acc + attn_b[m];
    }
    __syncthreads();

    // softmax over 64 scores (wave 0)
    if (w == 0) {
        float s = sc[lane];
        float mx = s;
        #pragma unroll
        for (int off = 32; off > 0; off >>= 1) mx = fmaxf(mx, __shfl_xor(mx, off, 64));
        float e = expf(s - mx);
        float sum = e;
        #pragma unroll
        for (int off = 32; off > 0; off >>= 1) sum += __shfl_xor(sum, off, 64);
        float wv = e / sum;
        wsm[lane] = wv;
        out_attn[lane] = wv;
    }
    __syncthreads();

    // context: thread t owns column t (coalesced across enc rows)
    float acc = 0.f;
    #pragma unroll 8
    for (int m = 0; m < MAXLEN; ++m)
        acc += wsm[m] * enc[(size_t)m * HIDDEN + t];
    ws_ctx[t] = acc;
}

// K2: 256 blocks x 256 threads (wave per row): x[j] = relu(dot(concat(emb_row, ctx), comb_W[j]) + comb_b[j])
__global__ void k_combine(const int* __restrict__ token,
                          const float* __restrict__ emb,
                          const float* __restrict__ ws_ctx,
                          const float* __restrict__ comb_W,
                          const float* __restrict__ comb_b,
                          float* __restrict__ ws_x) {
    const int wid = threadIdx.x >> 6, lane = threadIdx.x & 63;
    const int j = blockIdx.x * 4 + wid;
    const float* erow = emb + (size_t)token[0] * HIDDEN;
    const float4* Wrow = (const float4*)(comb_W + (size_t)j * 2 * HIDDEN);
    float acc = 0.f;
    #pragma unroll
    for (int it = 0; it < 8; ++it) {
        int i = lane + it * 64;          // 0..511 float4s
        float4 w4 = Wrow[i];
        int k = i * 4;
        const float* src = (k < HIDDEN) ? (erow + k) : (ws_ctx + k - HIDDEN);
        float4 c4 = *(const float4*)src;
        acc += w4.x * c4.x + w4.y * c4.y + w4.z * c4.z + w4.w * c4.w;
    }
    acc = wave_reduce_sum(acc);
    if (lane == 0) ws_x[j] = fmaxf(acc + comb_b[j], 0.f);
}

// K3: 1024 blocks x 384 threads: block j, wave q computes gate-dot q; thread 0 combines.
__global__ __launch_bounds__(384) void k_gru(
    const float* __restrict__ ws_x,
    const float* __restrict__ hidden,
    const float* __restrict__ W_ih,
    const float* __restrict__ W_hh,
    const float* __restrict__ b_ih,
    const float* __restrict__ b_hh,
    float* __restrict__ ws_h,
    float* __restrict__ out_h)
{
    __shared__ float dval[6];
    const int j = blockIdx.x;
    const int q = threadIdx.x >> 6, lane = threadIdx.x & 63;
    const float* row = (q < 3)
        ? (W_ih + (size_t)(j + q * HIDDEN) * HIDDEN)
        : (W_hh + (size_t)(j + (q - 3) * HIDDEN) * HIDDEN);
    const float* vec = (q < 3) ? ws_x : hidden;
    const float4* W4 = (const float4*)row;
    const float4* v4 = (const float4*)vec;
    float acc = 0.f;
    #pragma unroll
    for (int it = 0; it < 4; ++it) {
        int i = lane + it * 64;          // 0..255 float4s
        float4 a = W4[i];
        float4 b = v4[i];
        acc += a.x * b.x + a.y * b.y + a.z * b.z + a.w * b.w;
    }
    acc = wave_reduce_sum(acc);
    if (lane == 0) dval[q] = acc;
    __syncthreads();
    if (threadIdx.x == 0) {
        float i_r = dval[0] + b_ih[j];
        float i_z = dval[1] + b_ih[j + HIDDEN];
        float i_n = dval[2] + b_ih[j + 2 * HIDDEN];
        float h_r = dval[3] + b_hh[j];
        float h_z = dval[4] + b_hh[j + HIDDEN];
        float h_n = dval[5] + b_hh[j + 2 * HIDDEN];
        float r = 1.f / (1.f + expf(-(i_r + h_r)));
        float z = 1.f / (1.f + expf(-(i_z + h_z)));
        float n = tanhf(i_n + r * h_n);
        float h0v = hidden[j];
        float hn = (1.f - z) * n + z * h0v;
        ws_h[j] = hn;
        out_h[j] = hn;
    }
}

// K4: logits (round-7 version, known-good): 4 rows/wave, h in registers.
__global__ __launch_bounds__(256) void k_logits(
    const float* __restrict__ ws_h,
    const float* __restrict__ out_W,
    const float* __restrict__ out_b,
    float* __restrict__ out_logits)
{
    const int t = threadIdx.x;
    const int wid = t >> 6, lane = t & 63;
    const float4* h4 = (const float4*)ws_h;
    const float4 hv0 = h4[lane];
    const float4 hv1 = h4[lane + 64];
    const float4 hv2 = h4[lane + 128];
    const float4 hv3 = h4[lane + 192];

    const int base = blockIdx.x * 16 + wid * 4;
    float acc[4];
    #pragma unroll
    for (int r = 0; r < 4; ++r) {
        int v = base + r;
        if (v > VOCAB - 1) v = VOCAB - 1;     // clamp: duplicate read, discarded
        const float4* W = (const float4*)(out_W + (size_t)v * HIDDEN);
        float4 a0 = W[lane];
        float4 a1 = W[lane + 64];
        float4 a2 = W[lane + 128];
        float4 a3 = W[lane + 192];
        float s;
        s  = a0.x * hv0.x + a0.y * hv0.y + a0.z * hv0.z + a0.w * hv0.w;
        s += a1.x * hv1.x + a1.y * hv1.y + a1.z * hv1.z + a1.w * hv1.w;
        s += a2.x * hv2.x + a2.y * hv2.y + a2.z * hv2.z + a2.w * hv2.w;
        s += a3.x * hv3.x + a3.y * hv3.y + a3.z * hv3.z + a3.w * hv3.w;
        acc[r] = s;
    }
    #pragma unroll
    for (int r = 0; r < 4; ++r)
        acc[r] = wave_reduce_sum(acc[r]);
    if (lane == 0) {
        #pragma unroll
        for (int r = 0; r < 4; ++r) {
            const int v = base + r;
            if (v < VOCAB) out_logits[v] = acc[r] + out_b[v];
        }
    }
}

extern "C" void kernel_launch(void* const* d_in, const int* in_sizes, int n_in,
                              void* d_out, int out_size, void* d_ws, size_t ws_size,
                              hipStream_t stream) {
    const int*   token  = (const int*)d_in[0];
    const float* hidden = (const float*)d_in[1];
    const float* enc    = (const float*)d_in[2];
    const float* emb    = (const float*)d_in[3];
    const float* attn_W = (const float*)d_in[4];
    const float* attn_b = (const float*)d_in[5];
    const float* comb_W = (const float*)d_in[6];
    const float* comb_b = (const float*)d_in[7];
    const float* W_ih   = (const float*)d_in[8];
    const float* W_hh   = (const float*)d_in[9];
    const float* b_ih   = (const float*)d_in[10];
    const float* b_hh   = (const float*)d_in[11];
    const float* out_W  = (const float*)d_in[12];
    const float* out_b  = (const float*)d_in[13];

    float* out = (float*)d_out;
    float* out_logits = out;                       // [50257]
    float* out_h      = out + VOCAB;               // [1024]
    float* out_attn   = out + VOCAB + HIDDEN;      // [64]

    float* ws = (float*)d_ws;
    float* ws_ctx = ws;            // [1024]
    float* ws_x   = ws + 1024;     // [1024]
    float* ws_h   = ws + 2048;     // [1024]

    k_prelude<<<1, 1024, 0, stream>>>(token, emb, hidden, enc, attn_W, attn_b,
                                      ws_ctx, out_attn);
    k_combine<<<HIDDEN / 4, 256, 0, stream>>>(token, emb, ws_ctx, comb_W, comb_b, ws_x);
    k_gru<<<HIDDEN, 384, 0, stream>>>(ws_x, hidden, W_ih, W_hh, b_ih, b_hh, ws_h, out_h);
    k_logits<<<(VOCAB + 15) / 16, 256, 0, stream>>>(ws_h, out_W, out_b, out_logits);
}

// Round 10
// 51.950 us; speedup vs baseline: 1.1400x; 1.1093x over previous
//
#include <hip/hip_runtime.h>
#include <math.h>

#define HIDDEN 1024
#define VOCAB  50257
#define MAXLEN 64

__device__ __forceinline__ float wave_reduce_sum(float v) {
    #pragma unroll
    for (int off = 32; off > 0; off >>= 1)
        v += __shfl_down(v, off, 64);
    return v;
}

// K1 "front": all work that depends ONLY on kernel inputs (no chain deps):
//   blocks 0-15    : scores rows (wave/row, 64 rows)
//   blocks 16-783  : gh = W_hh @ h0 + b_hh (3072 rows, wave/row)   [12 MB]
//   blocks 784-1039: cemb[j] = dot(emb_row, comb_W[j][0:1024])      [4 MB]
__global__ __launch_bounds__(256) void k_front(
    const int* __restrict__ token,
    const float* __restrict__ emb,
    const float* __restrict__ hidden,
    const float* __restrict__ attn_W,
    const float* __restrict__ attn_b,
    const float* __restrict__ W_hh,
    const float* __restrict__ b_hh,
    const float* __restrict__ comb_W,
    float* __restrict__ ws_sc,     // [64]
    float* __restrict__ ws_gh,     // [3072]
    float* __restrict__ ws_cemb)   // [1024]
{
    const int b = blockIdx.x;
    const int wid = threadIdx.x >> 6, lane = threadIdx.x & 63;

    if (b < 16) {
        // scores: wave per row m
        const int m = b * 4 + wid;
        const float4* e4 = (const float4*)(emb + (size_t)token[0] * HIDDEN);
        const float4* h4 = (const float4*)hidden;
        const float4* Wr = (const float4*)(attn_W + (size_t)m * 2 * HIDDEN);
        float acc = 0.f;
        #pragma unroll
        for (int it = 0; it < 8; ++it) {
            int i = lane + it * 64;                 // 0..511 float4s
            float4 a = Wr[i];
            float4 c = (i < 256) ? e4[i] : h4[i - 256];
            acc += a.x * c.x + a.y * c.y + a.z * c.z + a.w * c.w;
        }
        acc = wave_reduce_sum(acc);
        if (lane == 0) ws_sc[m] = acc + attn_b[m];
    } else if (b < 784) {
        // gh: wave per row
        const int row = (b - 16) * 4 + wid;         // 0..3071
        const float4* Wr = (const float4*)(W_hh + (size_t)row * HIDDEN);
        const float4* h4 = (const float4*)hidden;
        float acc = 0.f;
        #pragma unroll
        for (int it = 0; it < 4; ++it) {
            int i = lane + it * 64;                 // 0..255 float4s
            float4 a = Wr[i];
            float4 c = h4[i];
            acc += a.x * c.x + a.y * c.y + a.z * c.z + a.w * c.w;
        }
        acc = wave_reduce_sum(acc);
        if (lane == 0) ws_gh[row] = acc + b_hh[row];
    } else {
        // cemb: wave per row j (emb-half of combine)
        const int j = (b - 784) * 4 + wid;          // 0..1023
        const float4* Wr = (const float4*)(comb_W + (size_t)j * 2 * HIDDEN);
        const float4* e4 = (const float4*)(emb + (size_t)token[0] * HIDDEN);
        float acc = 0.f;
        #pragma unroll
        for (int it = 0; it < 4; ++it) {
            int i = lane + it * 64;                 // 0..255 float4s (first half)
            float4 a = Wr[i];
            float4 c = e4[i];
            acc += a.x * c.x + a.y * c.y + a.z * c.z + a.w * c.w;
        }
        acc = wave_reduce_sum(acc);
        if (lane == 0) ws_cemb[j] = acc;
    }
}

// K2: softmax (redundant, 1 wave) + context slice. 16 blocks x 64 threads,
// block b owns cols 64b..64b+63 (16 KB of enc each -> spread across 16 CUs).
__global__ __launch_bounds__(64) void k_smctx(
    const float* __restrict__ ws_sc,
    const float* __restrict__ enc,
    float* __restrict__ ws_ctx,
    float* __restrict__ out_attn)
{
    __shared__ float wsm[MAXLEN];
    const int t = threadIdx.x;                      // 0..63
    float s = ws_sc[t];
    float mx = s;
    #pragma unroll
    for (int off = 32; off > 0; off >>= 1) mx = fmaxf(mx, __shfl_xor(mx, off, 64));
    float e = expf(s - mx);
    float sum = e;
    #pragma unroll
    for (int off = 32; off > 0; off >>= 1) sum += __shfl_xor(sum, off, 64);
    float wv = e / sum;
    wsm[t] = wv;
    if (blockIdx.x == 0) out_attn[t] = wv;
    __syncthreads();

    const int col = blockIdx.x * 64 + t;
    float acc = 0.f;
    #pragma unroll 8
    for (int m = 0; m < MAXLEN; ++m)
        acc += wsm[m] * enc[(size_t)m * HIDDEN + col];
    ws_ctx[col] = acc;
}

// K3: combine, ctx-half only. 256 blocks x 256 threads (wave per row j).
__global__ __launch_bounds__(256) void k_combine(
    const float* __restrict__ ws_ctx,
    const float* __restrict__ ws_cemb,
    const float* __restrict__ comb_W,
    const float* __restrict__ comb_b,
    float* __restrict__ ws_x)
{
    const int wid = threadIdx.x >> 6, lane = threadIdx.x & 63;
    const int j = blockIdx.x * 4 + wid;
    const float4* Wr = (const float4*)(comb_W + (size_t)j * 2 * HIDDEN + HIDDEN);
    const float4* c4 = (const float4*)ws_ctx;
    float acc = 0.f;
    #pragma unroll
    for (int it = 0; it < 4; ++it) {
        int i = lane + it * 64;                     // 0..255 float4s (second half)
        float4 a = Wr[i];
        float4 c = c4[i];
        acc += a.x * c.x + a.y * c.y + a.z * c.z + a.w * c.w;
    }
    acc = wave_reduce_sum(acc);
    if (lane == 0) ws_x[j] = fmaxf(acc + ws_cemb[j] + comb_b[j], 0.f);
}

// K4: GRU, gi-half only (gh precomputed). 1024 blocks x 192 threads:
// wave q in {0,1,2} computes dot(W_ih[j+q*H], x); thread 0 combines gates.
__global__ __launch_bounds__(192) void k_gru(
    const float* __restrict__ ws_x,
    const float* __restrict__ ws_gh,
    const float* __restrict__ hidden,
    const float* __restrict__ W_ih,
    const float* __restrict__ b_ih,
    float* __restrict__ ws_h,
    float* __restrict__ out_h)
{
    __shared__ float dval[3];
    const int j = blockIdx.x;
    const int q = threadIdx.x >> 6, lane = threadIdx.x & 63;
    const float4* W4 = (const float4*)(W_ih + (size_t)(j + q * HIDDEN) * HIDDEN);
    const float4* v4 = (const float4*)ws_x;
    float acc = 0.f;
    #pragma unroll
    for (int it = 0; it < 4; ++it) {
        int i = lane + it * 64;                     // 0..255 float4s
        float4 a = W4[i];
        float4 b = v4[i];
        acc += a.x * b.x + a.y * b.y + a.z * b.z + a.w * b.w;
    }
    acc = wave_reduce_sum(acc);
    if (lane == 0) dval[q] = acc;
    __syncthreads();
    if (threadIdx.x == 0) {
        float i_r = dval[0] + b_ih[j];
        float i_z = dval[1] + b_ih[j + HIDDEN];
        float i_n = dval[2] + b_ih[j + 2 * HIDDEN];
        float h_r = ws_gh[j];
        float h_z = ws_gh[j + HIDDEN];
        float h_n = ws_gh[j + 2 * HIDDEN];
        float r = 1.f / (1.f + expf(-(i_r + h_r)));
        float z = 1.f / (1.f + expf(-(i_z + h_z)));
        float n = tanhf(i_n + r * h_n);
        float h0v = hidden[j];
        float hn = (1.f - z) * n + z * h0v;
        ws_h[j] = hn;
        out_h[j] = hn;
    }
}

// K5: logits (round-7 version, known-good): 4 rows/wave, h in registers.
__global__ __launch_bounds__(256) void k_logits(
    const float* __restrict__ ws_h,
    const float* __restrict__ out_W,
    const float* __restrict__ out_b,
    float* __restrict__ out_logits)
{
    const int t = threadIdx.x;
    const int wid = t >> 6, lane = t & 63;
    const float4* h4 = (const float4*)ws_h;
    const float4 hv0 = h4[lane];
    const float4 hv1 = h4[lane + 64];
    const float4 hv2 = h4[lane + 128];
    const float4 hv3 = h4[lane + 192];

    const int base = blockIdx.x * 16 + wid * 4;
    float acc[4];
    #pragma unroll
    for (int r = 0; r < 4; ++r) {
        int v = base + r;
        if (v > VOCAB - 1) v = VOCAB - 1;     // clamp: duplicate read, discarded
        const float4* W = (const float4*)(out_W + (size_t)v * HIDDEN);
        float4 a0 = W[lane];
        float4 a1 = W[lane + 64];
        float4 a2 = W[lane + 128];
        float4 a3 = W[lane + 192];
        float s;
        s  = a0.x * hv0.x + a0.y * hv0.y + a0.z * hv0.z + a0.w * hv0.w;
        s += a1.x * hv1.x + a1.y * hv1.y + a1.z * hv1.z + a1.w * hv1.w;
        s += a2.x * hv2.x + a2.y * hv2.y + a2.z * hv2.z + a2.w * hv2.w;
        s += a3.x * hv3.x + a3.y * hv3.y + a3.z * hv3.z + a3.w * hv3.w;
        acc[r] = s;
    }
    #pragma unroll
    for (int r = 0; r < 4; ++r)
        acc[r] = wave_reduce_sum(acc[r]);
    if (lane == 0) {
        #pragma unroll
        for (int r = 0; r < 4; ++r) {
            const int v = base + r;
            if (v < VOCAB) out_logits[v] = acc[r] + out_b[v];
        }
    }
}

extern "C" void kernel_launch(void* const* d_in, const int* in_sizes, int n_in,
                              void* d_out, int out_size, void* d_ws, size_t ws_size,
                              hipStream_t stream) {
    const int*   token  = (const int*)d_in[0];
    const float* hidden = (const float*)d_in[1];
    const float* enc    = (const float*)d_in[2];
    const float* emb    = (const float*)d_in[3];
    const float* attn_W = (const float*)d_in[4];
    const float* attn_b = (const float*)d_in[5];
    const float* comb_W = (const float*)d_in[6];
    const float* comb_b = (const float*)d_in[7];
    const float* W_ih   = (const float*)d_in[8];
    const float* W_hh   = (const float*)d_in[9];
    const float* b_ih   = (const float*)d_in[10];
    const float* b_hh   = (const float*)d_in[11];
    const float* out_W  = (const float*)d_in[12];
    const float* out_b  = (const float*)d_in[13];

    float* out = (float*)d_out;
    float* out_logits = out;                       // [50257]
    float* out_h      = out + VOCAB;               // [1024]
    float* out_attn   = out + VOCAB + HIDDEN;      // [64]

    float* ws = (float*)d_ws;
    float* ws_sc   = ws;              // [64]
    float* ws_gh   = ws + 64;         // [3072]
    float* ws_cemb = ws + 3136;       // [1024]
    float* ws_ctx  = ws + 4160;       // [1024]
    float* ws_x    = ws + 5184;       // [1024]
    float* ws_h    = ws + 6208;       // [1024]

    k_front<<<1040, 256, 0, stream>>>(token, emb, hidden, attn_W, attn_b,
                                      W_hh, b_hh, comb_W, ws_sc, ws_gh, ws_cemb);
    k_smctx<<<16, 64, 0, stream>>>(ws_sc, enc, ws_ctx, out_attn);
    k_combine<<<HIDDEN / 4, 256, 0, stream>>>(ws_ctx, ws_cemb, comb_W, comb_b, ws_x);
    k_gru<<<HIDDEN, 192, 0, stream>>>(ws_x, ws_gh, hidden, W_ih, b_ih, ws_h, out_h);
    k_logits<<<(VOCAB + 15) / 16, 256, 0, stream>>>(ws_h, out_W, out_b, out_logits);
}